// Round 8
// baseline (492.778 us; speedup 1.0000x reference)
//
#include <hip/hip_runtime.h>
#include <math.h>

// Fixed problem shape: B=8, N=M=4096, 3-D f32 points.
#define NPTS   4096
#define NB     8
#define TPB    1024
#define WAVES  16
#define QPW    16              // queries per wave, held in SGPRs
#define QBLK   (WAVES * QPW)   // 256 queries per block
#define CHUNK  2048            // candidates per block (half cloud)
#define NCHUNK (NPTS / CHUNK)  // 2
#define GRID1  (2 * NB * (NPTS / QBLK) * NCHUNK)   // 512
#define NQTOT  65536           // 2 * 8 * 4096 queries

// monotone float->uint mapping (total order == float order, handles negatives)
__device__ __forceinline__ unsigned f2mono(float f) {
    unsigned b = __float_as_uint(f);
    unsigned mask = (unsigned)(((int)b) >> 31) | 0x80000000u;
    return b ^ mask;
}
__device__ __forceinline__ float mono2f(unsigned u) {
    unsigned mask = (u >> 31) ? 0x80000000u : 0xFFFFFFFFu;
    return __uint_as_float(u ^ mask);
}
// force a wave-uniform float into an SGPR (enables v_fma_f32 s,v,v)
__device__ __forceinline__ float sgpr_f(float v) {
    return __uint_as_float(__builtin_amdgcn_readfirstlane(__float_as_uint(v)));
}

// ws layout: u64 res[NCHUNK][NQTOT] packed (mono(dist)<<32)|idx, plain stores.

// Kernel 1: queries in SGPR, candidates per-lane from LDS (lane owns idx 64k+lane).
// Inner loop: 2 ds_read_b128 (immediate offsets, zero addr math) + per query
// {2 FMA-chains + v_min3 + pair-index track}. Argmin recovered by shuffle-min +
// ballot + exact 2-candidate FMA replay on the winning lane.
__global__ __launch_bounds__(TPB, 8) void chamfer8_scan(
    const float* __restrict__ xyz1, const float* __restrict__ xyz2,
    unsigned long long* __restrict__ res, float* __restrict__ out)
{
    __shared__ float4 sc[CHUNK];     // 32 KB: (-2x, -2y, -2z, |r|^2)

    int bid   = blockIdx.x;
    int dir   = bid >> 8;            // 256 blocks per direction
    int b     = (bid >> 5) & 7;
    int qblk  = (bid >> 1) & 15;
    int chunk = bid & 1;

    int tid  = threadIdx.x;
    int lane = tid & 63;
    int wid  = tid >> 6;

    if (bid == 0 && tid == 0) { out[0] = 0.f; out[1] = 0.f; }  // out poisoned

    const float* qb = (dir ? xyz2 : xyz1) + (size_t)b * NPTS * 3;
    const float* rb = (dir ? xyz1 : xyz2) + ((size_t)b * NPTS + chunk * CHUNK) * 3;

    // ---- stage CHUNK candidates, prescaled: 512 threads x 4 points ----
    if (tid < CHUNK / 4) {
        const float4* rb4 = (const float4*)rb;   // 24 KB, 16B-aligned
        float4 v0 = rb4[tid * 3 + 0];
        float4 v1 = rb4[tid * 3 + 1];
        float4 v2 = rb4[tid * 3 + 2];
        int p = tid * 4;
        sc[p + 0] = make_float4(-2.f * v0.x, -2.f * v0.y, -2.f * v0.z,
                                fmaf(v0.x, v0.x, fmaf(v0.y, v0.y, v0.z * v0.z)));
        sc[p + 1] = make_float4(-2.f * v0.w, -2.f * v1.x, -2.f * v1.y,
                                fmaf(v0.w, v0.w, fmaf(v1.x, v1.x, v1.y * v1.y)));
        sc[p + 2] = make_float4(-2.f * v1.z, -2.f * v1.w, -2.f * v2.x,
                                fmaf(v1.z, v1.z, fmaf(v1.w, v1.w, v2.x * v2.x)));
        sc[p + 3] = make_float4(-2.f * v2.y, -2.f * v2.z, -2.f * v2.w,
                                fmaf(v2.y, v2.y, fmaf(v2.z, v2.z, v2.w * v2.w)));
    }

    // ---- this wave's 16 queries -> SGPRs (wave-uniform address) ----
    const float* qsrc = qb + (qblk * QBLK + wid * QPW) * 3;
    float qx[QPW], qy[QPW], qz[QPW];
    #pragma unroll
    for (int i = 0; i < QPW; ++i) {
        qx[i] = sgpr_f(qsrc[3 * i + 0]);
        qy[i] = sgpr_f(qsrc[3 * i + 1]);
        qz[i] = sgpr_f(qsrc[3 * i + 2]);
    }
    __syncthreads();

    // ---- scan: lane owns candidates {64k + lane}; 32 rounds = 16 pair-iters ----
    float bE[QPW];
    int   kb[QPW];
    #pragma unroll
    for (int i = 0; i < QPW; ++i) { bE[i] = INFINITY; kb[i] = 0; }

    const float4* cp = &sc[lane];    // all ds_reads: base + immediate offset
    #pragma unroll
    for (int it = 0; it < CHUNK / 128; ++it) {   // 16 iterations
        float4 c0 = cp[it * 128];        // candidate 128*it + lane
        float4 c1 = cp[it * 128 + 64];   // candidate 128*it + 64 + lane
        #pragma unroll
        for (int i = 0; i < QPW; ++i) {
            float d0 = fmaf(qx[i], c0.x, fmaf(qy[i], c0.y, fmaf(qz[i], c0.z, c0.w)));
            float d1 = fmaf(qx[i], c1.x, fmaf(qy[i], c1.y, fmaf(qz[i], c1.z, c1.w)));
            float nb = fminf(fminf(bE[i], d0), d1);    // v_min3_f32
            kb[i] = (nb < bE[i]) ? it : kb[i];         // strict <: keep earliest
            bE[i] = nb;
        }
    }

    // ---- per query: wave min + winning-lane exact replay + packed store ----
    unsigned qglob0 = (unsigned)(dir * (NB * NPTS) + b * NPTS + qblk * QBLK + wid * QPW);
    #pragma unroll
    for (int i = 0; i < QPW; ++i) {
        float mv = bE[i];
        #pragma unroll
        for (int off = 32; off > 0; off >>= 1)
            mv = fminf(mv, __shfl_xor(mv, off, 64));
        unsigned long long blt = __ballot(bE[i] == mv);
        int l0 = __ffsll((unsigned long long)blt) - 1;
        if (lane == l0) {
            int slot0 = kb[i] * 128 + lane;
            float4 c0 = sc[slot0];
            float4 c1 = sc[slot0 + 64];
            float d0 = fmaf(qx[i], c0.x, fmaf(qy[i], c0.y, fmaf(qz[i], c0.z, c0.w)));
            int idx = chunk * CHUNK + ((d0 == mv) ? slot0 : slot0 + 64);
            float q2 = fmaf(qx[i], qx[i], fmaf(qy[i], qy[i], qz[i] * qz[i]));
            float dist = mv + q2;        // |q|^2 + min(r^2 - 2 q.r)
            res[(size_t)chunk * NQTOT + qglob0 + i] =
                ((unsigned long long)f2mono(dist) << 32) | (unsigned)idx;
        }
    }
}

// Kernel 2: combine chunks (u64 min == first-min on (dist,idx)), normal term,
// block partial sums -> 2 atomicAdds into out (zeroed by kernel 1).
__global__ __launch_bounds__(256) void chamfer8_finalize(
    const float* __restrict__ nrm1, const float* __restrict__ nrm2,
    const unsigned long long* __restrict__ res, float* __restrict__ out)
{
    __shared__ float fin[8];
    int tid = threadIdx.x;
    int gq  = blockIdx.x * 256 + tid;

    unsigned long long pk = res[gq];
    #pragma unroll
    for (int c = 1; c < NCHUNK; ++c) {
        unsigned long long p2 = res[(size_t)c * NQTOT + gq];
        pk = p2 < pk ? p2 : pk;
    }
    float dist = mono2f((unsigned)(pk >> 32));
    int   idx  = (int)(pk & 0xFFFFFFFFu);          // 0..4095

    int d2  = gq >> 15;            // direction
    int rem = gq & 32767;          // b*4096 + n
    int bb  = rem >> 12;           // batch

    const float* a3 = (d2 ? nrm2 : nrm1) + (size_t)rem * 3;
    const float* t3 = (d2 ? nrm1 : nrm2) + ((size_t)bb * NPTS + idx) * 3;
    float ax = a3[0], ay = a3[1], az = a3[2];
    float ia = 1.f / fmaxf(sqrtf(fmaf(ax, ax, fmaf(ay, ay, az * az))), 1e-12f);
    ax *= ia; ay *= ia; az *= ia;
    float bx = t3[0], by = t3[1], bz = t3[2];
    float ib = 1.f / fmaxf(sqrtf(fmaf(bx, bx, fmaf(by, by, bz * bz))), 1e-12f);
    bx *= ib; by *= ib; bz *= ib;
    float ex = ax - bx, ey = ay - by, ez = az - bz;
    float px = ax + bx, py = ay + by, pz = az + bz;
    float dm = fmaf(ex, ex, fmaf(ey, ey, ez * ez));
    float dp = fmaf(px, px, fmaf(py, py, pz * pz));
    float nd = fminf(dm, dp);

    for (int off = 32; off > 0; off >>= 1) {
        dist += __shfl_down(dist, off, 64);
        nd   += __shfl_down(nd,   off, 64);
    }
    int wave = tid >> 6, lane = tid & 63;
    if (lane == 0) { fin[wave * 2] = dist; fin[wave * 2 + 1] = nd; }
    __syncthreads();
    if (tid == 0) {
        const float inv = 1.0f / 32768.0f;
        float a = (fin[0] + fin[2] + fin[4] + fin[6]) * inv;
        float c = (fin[1] + fin[3] + fin[5] + fin[7]) * inv;
        atomicAdd(&out[0], a);   // loss_xyz
        atomicAdd(&out[1], c);   // loss_normal
    }
}

extern "C" void kernel_launch(void* const* d_in, const int* in_sizes, int n_in,
                              void* d_out, int out_size, void* d_ws, size_t ws_size,
                              hipStream_t stream) {
    const float* xyz1 = (const float*)d_in[0];   // [8,4096,3]
    const float* xyz2 = (const float*)d_in[1];
    const float* nrm1 = (const float*)d_in[2];   // normal_rebuild
    const float* nrm2 = (const float*)d_in[3];   // normal_gt
    float* out = (float*)d_out;

    unsigned long long* res = (unsigned long long*)d_ws;   // 1 MB

    chamfer8_scan<<<GRID1, TPB, 0, stream>>>(xyz1, xyz2, res, out);
    chamfer8_finalize<<<NQTOT / 256, 256, 0, stream>>>(nrm1, nrm2, res, out);
}

// Round 9
// 90.814 us; speedup vs baseline: 5.4262x; 5.4262x over previous
//
#include <hip/hip_runtime.h>
#include <math.h>

// Fixed problem shape: B=8, N=M=4096, 3-D f32 points.
#define NPTS  4096
#define NB    8
#define TPB   1024
#define QB    256            // queries per block
#define HALF  2048           // candidates per block (half the cloud)
#define SEGS  16             // one wave per segment
#define CPS   (HALF / SEGS)  // 128 candidates per segment
#define GRID1 512            // 2 dirs * 8 batches * 16 qblks * 2 halves
#define NQTOT 65536          // 2 * 8 * 4096 queries

// ws layout: u64 res[2][NQTOT]  (per-half packed (distbits<<32)|idx, plain
// coalesced stores, no atomics).

// Kernel 1 (identical to the proven R5 scan): value-only min3 scan + exact
// argmin recovery via segment rescan; adds only the out[]-zeroing (block 0).
__global__ __launch_bounds__(TPB, 8) void chamfer9_scan(
    const float* __restrict__ xyz1, const float* __restrict__ xyz2,
    unsigned long long* __restrict__ res, float* __restrict__ out)
{
    __shared__ float4 sc[HALF];                    // 32 KB (x,y,z,|r|^2)
    __shared__ float  sBest[SEGS * QB];            // 16 KB
    __shared__ float  qMin[QB];
    __shared__ int    qSeg[QB];
    __shared__ float4 qM[QB];                      // (-2qx,-2qy,-2qz,|q|^2)
    __shared__ unsigned long long qPk[QB];         // 2 KB packed results

    int bid  = blockIdx.x;
    int dir  = bid >> 8;
    int b    = (bid >> 5) & 7;
    int qblk = (bid >> 1) & 15;
    int half = bid & 1;

    int tid  = threadIdx.x;
    int lane = tid & 63;
    int wid  = tid >> 6;

    if (bid == 0 && tid == 0) { out[0] = 0.f; out[1] = 0.f; }  // out poisoned

    const float* qb = (dir ? xyz2 : xyz1) + (size_t)b * NPTS * 3;
    const float* rb = (dir ? xyz1 : xyz2) + ((size_t)b * NPTS + half * HALF) * 3;

    // ---- stage 2048 candidates as (x,y,z,r^2) ----
    if (tid < 512) {
        const float4* rb4 = (const float4*)rb;     // 24 KB, 16B-aligned
        float4 v0 = rb4[tid * 3 + 0];
        float4 v1 = rb4[tid * 3 + 1];
        float4 v2 = rb4[tid * 3 + 2];
        int p = tid * 4;
        sc[p + 0] = make_float4(v0.x, v0.y, v0.z, fmaf(v0.x, v0.x, fmaf(v0.y, v0.y, v0.z * v0.z)));
        sc[p + 1] = make_float4(v0.w, v1.x, v1.y, fmaf(v0.w, v0.w, fmaf(v1.x, v1.x, v1.y * v1.y)));
        sc[p + 2] = make_float4(v1.z, v1.w, v2.x, fmaf(v1.z, v1.z, fmaf(v1.w, v1.w, v2.x * v2.x)));
        sc[p + 3] = make_float4(v2.y, v2.z, v2.w, fmaf(v2.y, v2.y, fmaf(v2.z, v2.z, v2.w * v2.w)));
    }
    __syncthreads();

    // ---- value-only scan: 4 queries/thread, 2 min3 chains each ----
    float mx[4], my[4], mz[4];
    #pragma unroll
    for (int u = 0; u < 4; ++u) {
        const float* p = qb + (qblk * QB + u * 64 + lane) * 3;
        mx[u] = -2.f * p[0]; my[u] = -2.f * p[1]; mz[u] = -2.f * p[2];
    }
    float bE[4], bO[4];
    #pragma unroll
    for (int u = 0; u < 4; ++u) { bE[u] = INFINITY; bO[u] = INFINITY; }

    int jb = wid * CPS;
    #pragma unroll 2
    for (int jo = 0; jo < CPS; jo += 4) {
        float4 c0 = sc[jb + jo + 0];   // broadcast reads (wave-uniform addr)
        float4 c1 = sc[jb + jo + 1];
        float4 c2 = sc[jb + jo + 2];
        float4 c3 = sc[jb + jo + 3];
        #pragma unroll
        for (int u = 0; u < 4; ++u) {
            float d0 = fmaf(mx[u], c0.x, fmaf(my[u], c0.y, fmaf(mz[u], c0.z, c0.w)));
            float d1 = fmaf(mx[u], c1.x, fmaf(my[u], c1.y, fmaf(mz[u], c1.z, c1.w)));
            float d2 = fmaf(mx[u], c2.x, fmaf(my[u], c2.y, fmaf(mz[u], c2.z, c2.w)));
            float d3 = fmaf(mx[u], c3.x, fmaf(my[u], c3.y, fmaf(mz[u], c3.z, c3.w)));
            bE[u] = fminf(fminf(bE[u], d0), d2);   // -> v_min3_f32
            bO[u] = fminf(fminf(bO[u], d1), d3);
        }
    }
    #pragma unroll
    for (int u = 0; u < 4; ++u)
        sBest[wid * QB + u * 64 + lane] = fminf(bE[u], bO[u]);
    __syncthreads();

    // ---- combine across segments (value + first winning segment) ----
    if (tid < QB) {
        float best = sBest[tid]; int bs = 0;
        #pragma unroll
        for (int s = 1; s < SEGS; ++s) {
            float v = sBest[s * QB + tid];
            if (v < best) { best = v; bs = s; }   // strict <: lowest seg on tie
        }
        qMin[tid] = best; qSeg[tid] = bs;
        const float* p = qb + (qblk * QB + tid) * 3;
        float qx = p[0], qy = p[1], qz = p[2];
        qM[tid] = make_float4(-2.f * qx, -2.f * qy, -2.f * qz,
                              fmaf(qx, qx, fmaf(qy, qy, qz * qz)));
    }
    __syncthreads();

    // ---- rescan winning segment: exact FMA replay + ballot-ffs argmin ----
    #pragma unroll 4
    for (int k = 0; k < 16; ++k) {
        int q = wid * 16 + k;
        float minv = qMin[q];
        int   seg  = qSeg[q];
        float4 m   = qM[q];
        float4 ca  = sc[seg * CPS + lane];
        float4 cb  = sc[seg * CPS + 64 + lane];
        float da = fmaf(m.x, ca.x, fmaf(m.y, ca.y, fmaf(m.z, ca.z, ca.w)));
        float db = fmaf(m.x, cb.x, fmaf(m.y, cb.y, fmaf(m.z, cb.z, cb.w)));
        unsigned long long ba = __ballot(da == minv);
        unsigned long long bb = __ballot(db == minv);
        if (lane == 0) {
            int off = ba ? (__ffsll(ba) - 1) : (64 + __ffsll(bb) - 1);
            int gidx = half * HALF + seg * CPS + off;     // 0..4095
            float dist = fmaxf(minv + m.w, 0.f);          // |q|^2 + min(r^2-2qr)
            qPk[q] = ((unsigned long long)__float_as_uint(dist) << 32)
                     | (unsigned)gidx;
        }
    }
    __syncthreads();

    // ---- coalesced store of 256 packed results ----
    if (tid < QB) {
        unsigned qglob = (unsigned)(dir * (NB * NPTS) + b * NPTS + qblk * QB + tid);
        res[(size_t)half * NQTOT + qglob] = qPk[tid];
    }
}

// Kernel 2: combine halves (u64 min == first-min on (dist,idx)), normal term,
// block partial sums -> 2 atomicAdds into out (zeroed by kernel 1).
__global__ __launch_bounds__(256) void chamfer9_finalize(
    const float* __restrict__ nrm1, const float* __restrict__ nrm2,
    const unsigned long long* __restrict__ res, float* __restrict__ out)
{
    __shared__ float fin[8];
    int tid = threadIdx.x;
    int gq  = blockIdx.x * 256 + tid;

    unsigned long long pk0 = res[gq];
    unsigned long long pk1 = res[NQTOT + gq];
    unsigned long long pk  = pk0 < pk1 ? pk0 : pk1;
    float dist = __uint_as_float((unsigned)(pk >> 32));
    int   idx  = (int)(pk & 0xFFFFFFFFu);          // 0..4095

    int d2  = gq >> 15;            // direction
    int rem = gq & 32767;          // b*4096 + n
    int bb  = rem >> 12;           // batch

    const float* a3 = (d2 ? nrm2 : nrm1) + (size_t)rem * 3;
    const float* t3 = (d2 ? nrm1 : nrm2) + ((size_t)bb * NPTS + idx) * 3;
    float ax = a3[0], ay = a3[1], az = a3[2];
    float ia = 1.f / fmaxf(sqrtf(fmaf(ax, ax, fmaf(ay, ay, az * az))), 1e-12f);
    ax *= ia; ay *= ia; az *= ia;
    float bx = t3[0], by = t3[1], bz = t3[2];
    float ib = 1.f / fmaxf(sqrtf(fmaf(bx, bx, fmaf(by, by, bz * bz))), 1e-12f);
    bx *= ib; by *= ib; bz *= ib;
    float ex = ax - bx, ey = ay - by, ez = az - bz;
    float px = ax + bx, py = ay + by, pz = az + bz;
    float dm = fmaf(ex, ex, fmaf(ey, ey, ez * ez));
    float dp = fmaf(px, px, fmaf(py, py, pz * pz));
    float nd = fminf(dm, dp);

    for (int off = 32; off > 0; off >>= 1) {
        dist += __shfl_down(dist, off, 64);
        nd   += __shfl_down(nd,   off, 64);
    }
    int wave = tid >> 6, lane = tid & 63;
    if (lane == 0) { fin[wave * 2] = dist; fin[wave * 2 + 1] = nd; }
    __syncthreads();
    if (tid == 0) {
        const float inv = 1.0f / 32768.0f;
        float a = (fin[0] + fin[2] + fin[4] + fin[6]) * inv;
        float c = (fin[1] + fin[3] + fin[5] + fin[7]) * inv;
        atomicAdd(&out[0], a);   // loss_xyz
        atomicAdd(&out[1], c);   // loss_normal
    }
}

extern "C" void kernel_launch(void* const* d_in, const int* in_sizes, int n_in,
                              void* d_out, int out_size, void* d_ws, size_t ws_size,
                              hipStream_t stream) {
    const float* xyz1 = (const float*)d_in[0];   // [8,4096,3]
    const float* xyz2 = (const float*)d_in[1];
    const float* nrm1 = (const float*)d_in[2];   // normal_rebuild
    const float* nrm2 = (const float*)d_in[3];   // normal_gt
    float* out = (float*)d_out;

    unsigned long long* res = (unsigned long long*)d_ws;   // 1 MB

    chamfer9_scan<<<GRID1, TPB, 0, stream>>>(xyz1, xyz2, res, out);
    chamfer9_finalize<<<NQTOT / 256, 256, 0, stream>>>(nrm1, nrm2, res, out);
}